// Round 2
// baseline (355.263 us; speedup 1.0000x reference)
//
#include <hip/hip_runtime.h>
#include <math.h>

namespace {
constexpr int B = 8, C = 128, N = 2048, M = 512;
constexpr int NSPLIT = 8;
constexpr int MBLK = N / 128;   // 16 m-tiles per row in energy
constexpr float INV_SQRT_C = 0.08838834764831845f;  // 1/sqrt(128)
}

// ---------------- q,k,v = W @ x (per batch channel-mix) ----------------
__global__ __launch_bounds__(256) void qkv_kernel(
    const float* __restrict__ x, const float* __restrict__ Wq,
    const float* __restrict__ Wk, const float* __restrict__ Wv,
    float* __restrict__ q, float* __restrict__ k, float* __restrict__ v) {
  int n = blockIdx.x * 256 + threadIdx.x;
  int o0 = blockIdx.y * 4;   // 4 output channels per block -> W loads uniform
  int b = blockIdx.z;
  const float* xb = x + (size_t)b * C * N + n;
  float aq[4] = {}, ak[4] = {}, av[4] = {};
  #pragma unroll 4
  for (int c = 0; c < C; ++c) {
    float xv = xb[(size_t)c * N];
    #pragma unroll
    for (int j = 0; j < 4; ++j) {
      aq[j] = fmaf(Wq[(o0 + j) * C + c], xv, aq[j]);
      ak[j] = fmaf(Wk[(o0 + j) * C + c], xv, ak[j]);
      av[j] = fmaf(Wv[(o0 + j) * C + c], xv, av[j]);
    }
  }
  #pragma unroll
  for (int j = 0; j < 4; ++j) {
    size_t off = ((size_t)b * C + o0 + j) * N + n;
    q[off] = aq[j]; k[off] = ak[j]; v[off] = av[j];
  }
}

// -- Ae[b,n,m] = exp(q.k/sqrt(C)); rowpart[mb][b*N+n] = tile row partial --
__global__ __launch_bounds__(256) void energy_kernel(
    const float* __restrict__ q, const float* __restrict__ k,
    float* __restrict__ Ae, float* __restrict__ rowpart) {
  __shared__ float qs[32][128];
  __shared__ float ks[32][128];
  __shared__ float red[16][128];
  int t = threadIdx.x;
  int m0 = blockIdx.x * 128, n0 = blockIdx.y * 128, b = blockIdx.z;
  const float* qb = q + (size_t)b * C * N;
  const float* kb = k + (size_t)b * C * N;
  int tc = t & 15, tm = t >> 4;
  float acc[8][8] = {};
  for (int c0 = 0; c0 < C; c0 += 32) {
    __syncthreads();
    #pragma unroll
    for (int it = 0; it < 16; ++it) {
      int ii = it * 256 + t;
      int cc = ii >> 7, nn = ii & 127;
      qs[cc][nn] = qb[(size_t)(c0 + cc) * N + n0 + nn];
      ks[cc][nn] = kb[(size_t)(c0 + cc) * N + m0 + nn];
    }
    __syncthreads();
    #pragma unroll
    for (int cc = 0; cc < 32; ++cc) {
      float4 a0 = *(const float4*)&qs[cc][tc * 8];
      float4 a1 = *(const float4*)&qs[cc][tc * 8 + 4];
      float4 b0 = *(const float4*)&ks[cc][tm * 8];
      float4 b1 = *(const float4*)&ks[cc][tm * 8 + 4];
      float av[8] = {a0.x, a0.y, a0.z, a0.w, a1.x, a1.y, a1.z, a1.w};
      float bv[8] = {b0.x, b0.y, b0.z, b0.w, b1.x, b1.y, b1.z, b1.w};
      #pragma unroll
      for (int i = 0; i < 8; ++i)
        #pragma unroll
        for (int j = 0; j < 8; ++j)
          acc[i][j] = fmaf(av[i], bv[j], acc[i][j]);
    }
  }
  float rs[8];
  #pragma unroll
  for (int i = 0; i < 8; ++i) {
    float p[8];
    #pragma unroll
    for (int j = 0; j < 8; ++j) p[j] = expf(acc[i][j] * INV_SQRT_C);
    rs[i] = ((p[0] + p[1]) + (p[2] + p[3])) + ((p[4] + p[5]) + (p[6] + p[7]));
    size_t row = (size_t)b * N + n0 + tc * 8 + i;
    *(float4*)&Ae[row * N + m0 + tm * 8] = make_float4(p[0], p[1], p[2], p[3]);
    *(float4*)&Ae[row * N + m0 + tm * 8 + 4] = make_float4(p[4], p[5], p[6], p[7]);
  }
  #pragma unroll
  for (int i = 0; i < 8; ++i) red[tm][tc * 8 + i] = rs[i];
  __syncthreads();
  if (t < 128) {
    float s = 0.f;
    #pragma unroll
    for (int j = 0; j < 16; ++j) s += red[j][t];
    // deterministic slot write (no atomics)
    rowpart[(size_t)blockIdx.x * (B * N) + b * N + n0 + t] = s;
  }
}

// ------- invr[b,n] = 1 / (fixed-order sum of 16 row partials) ----------
__global__ __launch_bounds__(256) void rowred_kernel(
    const float* __restrict__ rowpart, float* __restrict__ invr) {
  int i = blockIdx.x * 256 + threadIdx.x;
  float s = 0.f;
  #pragma unroll
  for (int mb = 0; mb < MBLK; ++mb)
    s += rowpart[(size_t)mb * (B * N) + i];
  invr[i] = 1.0f / s;
}

// --- selpart[nch][b*N+m] = sum_{n in chunk} Ae[b,n,m] * invr[b,n] ------
__global__ __launch_bounds__(256) void colsum_kernel(
    const float* __restrict__ Ae, const float* __restrict__ invr,
    float* __restrict__ selpart) {
  int m = blockIdx.x * 256 + threadIdx.x;
  int nch = blockIdx.y, b = blockIdx.z;
  const float* Ab = Ae + (size_t)b * N * N;
  const float* ib = invr + b * N;
  float acc = 0.f;
  int n0 = nch * (N / 8);
  for (int n = n0; n < n0 + N / 8; ++n)
    acc = fmaf(Ab[(size_t)n * N + m], ib[n], acc);
  selpart[(size_t)nch * (B * N) + b * N + m] = acc;
}

// ----------- sel[b,m] = fixed-order sum of the 8 n-chunk partials -------
__global__ __launch_bounds__(256) void selred_kernel(
    const float* __restrict__ selpart, float* __restrict__ sel) {
  int i = blockIdx.x * 256 + threadIdx.x;
  float s = 0.f;
  #pragma unroll
  for (int nch = 0; nch < 8; ++nch)
    s += selpart[(size_t)nch * (B * N) + i];
  sel[i] = s;
}

// ------- exact stable-descending top-k via pairwise rank counting -------
__global__ __launch_bounds__(256) void topk_kernel(
    const float* __restrict__ sel, int* __restrict__ idx) {
  __shared__ float s[N];
  __shared__ int rsum[64][4];
  int b = blockIdx.y;
  int t = threadIdx.x;
  for (int i = t; i < N; i += 256) s[i] = sel[b * N + i];
  __syncthreads();
  int i = blockIdx.x * 64 + (t & 63);
  int jc = t >> 6;
  float val = s[i];
  int r = 0;
  for (int j = jc * 512; j < jc * 512 + 512; ++j) {
    float sj = s[j];
    r += (sj > val || (sj == val && j < i)) ? 1 : 0;
  }
  rsum[t & 63][jc] = r;
  __syncthreads();
  if (t < 64) {
    int rank = rsum[t][0] + rsum[t][1] + rsum[t][2] + rsum[t][3];
    if (rank < M) idx[b * M + rank] = blockIdx.x * 64 + t;
  }
}

// ---- out partials: part[ns][b][c][m] = sum_{n in split} w[m,n]*v[c,n] ---
__global__ __launch_bounds__(256) void out_kernel(
    const float* __restrict__ Ae, const float* __restrict__ invr,
    const float* __restrict__ v, const int* __restrict__ idx,
    float* __restrict__ part) {
  __shared__ float vt[32][133];   // [n'][c], padded stride (conflict-free)
  __shared__ float wt[32][133];   // [n'][m]
  __shared__ int ridx[128];
  __shared__ float rinv[128];
  int t = threadIdx.x;
  int m0 = blockIdx.x * 128;
  int ns = blockIdx.y;
  int b = blockIdx.z;
  if (t < 128) {
    int r = idx[b * M + m0 + t];
    ridx[t] = r;
    rinv[t] = invr[b * N + r];
  }
  __syncthreads();
  int tc = t & 15, tm = t >> 4;
  float acc[8][8] = {};
  const float* vb = v + (size_t)b * C * N;
  const float* Ab = Ae + (size_t)b * N * N;
  int nbeg = ns * (N / NSPLIT);
  for (int nb = nbeg; nb < nbeg + N / NSPLIT; nb += 32) {
    __syncthreads();
    #pragma unroll
    for (int it = 0; it < 16; ++it) {
      int ii = it * 256 + t;
      int c = ii >> 5, nn = ii & 31;
      vt[nn][c] = vb[(size_t)c * N + nb + nn];
    }
    #pragma unroll
    for (int it = 0; it < 16; ++it) {
      int ii = it * 256 + t;
      int mm = ii >> 5, nn = ii & 31;
      wt[nn][mm] = Ab[(size_t)ridx[mm] * N + nb + nn] * rinv[mm];
    }
    __syncthreads();
    #pragma unroll
    for (int nn = 0; nn < 32; ++nn) {
      float4 a0 = *(const float4*)&vt[nn][tc * 8];
      float4 a1 = *(const float4*)&vt[nn][tc * 8 + 4];
      float4 b0 = *(const float4*)&wt[nn][tm * 8];
      float4 b1 = *(const float4*)&wt[nn][tm * 8 + 4];
      float av[8] = {a0.x, a0.y, a0.z, a0.w, a1.x, a1.y, a1.z, a1.w};
      float wv[8] = {b0.x, b0.y, b0.z, b0.w, b1.x, b1.y, b1.z, b1.w};
      #pragma unroll
      for (int ci = 0; ci < 8; ++ci)
        #pragma unroll
        for (int mj = 0; mj < 8; ++mj)
          acc[ci][mj] = fmaf(av[ci], wv[mj], acc[ci][mj]);
    }
  }
  float* pb = part + ((size_t)ns * B + b) * C * M;
  #pragma unroll
  for (int ci = 0; ci < 8; ++ci) {
    size_t rowoff = (size_t)(tc * 8 + ci) * M + m0 + tm * 8;
    *(float4*)&pb[rowoff] = make_float4(acc[ci][0], acc[ci][1], acc[ci][2], acc[ci][3]);
    *(float4*)&pb[rowoff + 4] = make_float4(acc[ci][4], acc[ci][5], acc[ci][6], acc[ci][7]);
  }
}

// ----------------- deterministic reduce of the n-splits -----------------
__global__ __launch_bounds__(256) void reduce_kernel(
    const float* __restrict__ part, float* __restrict__ out) {
  int i = blockIdx.x * 256 + threadIdx.x;
  float a = 0.f;
  #pragma unroll
  for (int ns = 0; ns < NSPLIT; ++ns)
    a += part[(size_t)ns * (B * C * M) + i];
  out[i] = a;
}

extern "C" void kernel_launch(void* const* d_in, const int* in_sizes, int n_in,
                              void* d_out, int out_size, void* d_ws, size_t ws_size,
                              hipStream_t stream) {
  const float* x  = (const float*)d_in[0];
  const float* Wq = (const float*)d_in[1];
  const float* Wk = (const float*)d_in[2];
  const float* Wv = (const float*)d_in[3];
  // d_in[4] = npts_ds (==512, compile-time M)
  float* out = (float*)d_out;

  float* ws = (float*)d_ws;
  float* q       = ws;
  float* k       = q + (size_t)B * C * N;
  float* v       = k + (size_t)B * C * N;
  float* Ae      = v + (size_t)B * C * N;
  float* rowpart = Ae + (size_t)B * N * N;          // 16 * B*N
  float* invr    = rowpart + (size_t)MBLK * B * N;  // B*N
  float* selpart = invr + (size_t)B * N;            // 8 * B*N
  float* sel     = selpart + (size_t)8 * B * N;     // B*N
  int*   idx     = (int*)(sel + (size_t)B * N);     // B*M
  // part overlays q,k (dead after energy_kernel): NSPLIT*B*C*M == 2*B*C*N floats
  float* part    = q;

  qkv_kernel<<<dim3(N / 256, C / 4, B), 256, 0, stream>>>(x, Wq, Wk, Wv, q, k, v);
  energy_kernel<<<dim3(N / 128, N / 128, B), 256, 0, stream>>>(q, k, Ae, rowpart);
  rowred_kernel<<<dim3(B * N / 256), 256, 0, stream>>>(rowpart, invr);
  colsum_kernel<<<dim3(N / 256, 8, B), 256, 0, stream>>>(Ae, invr, selpart);
  selred_kernel<<<dim3(B * N / 256), 256, 0, stream>>>(selpart, sel);
  topk_kernel<<<dim3(N / 64, B), 256, 0, stream>>>(sel, idx);
  out_kernel<<<dim3(M / 128, NSPLIT, B), 256, 0, stream>>>(Ae, invr, v, idx, part);
  reduce_kernel<<<dim3(B * C * M / 256), 256, 0, stream>>>(part, out);
}

// Round 4
// 327.816 us; speedup vs baseline: 1.0837x; 1.0837x over previous
//
#include <hip/hip_runtime.h>
#include <math.h>

namespace {
constexpr int B = 8, C = 128, N = 2048, M = 512;
constexpr int NSPLIT = 8;       // part (NSPLIT*B*C*M fp32 = 16.8MB) must fit split region (25.2MB)
constexpr int MBLK = N / 128;   // 16 m-tiles per row in energy
constexpr float INV_SQRT_C = 0.08838834764831845f;  // 1/sqrt(128)
}

typedef __attribute__((ext_vector_type(8))) short short8;
typedef __attribute__((ext_vector_type(16))) float f32x16;
typedef unsigned short ushort_t;
typedef unsigned int u32;

__device__ inline void async16(const void* g, void* l) {
  typedef const __attribute__((address_space(1))) u32* gp_t;
  typedef __attribute__((address_space(3))) u32* lp_t;
  __builtin_amdgcn_global_load_lds((gp_t)g, (lp_t)l, 16, 0, 0);
}

__device__ inline ushort_t f2bf(float f) {   // round-to-nearest-even bf16
  union { float f; u32 u; } a; a.f = f;
  u32 r = a.u + 0x7fffu + ((a.u >> 16) & 1u);
  return (ushort_t)(r >> 16);
}
__device__ inline float bf2f(ushort_t h) {
  union { u32 u; float f; } a; a.u = ((u32)h) << 16; return a.f;
}

// -- q,k: 3-term bf16 split [term][b][n][c]; v: fp32 [b][c][n] ----------
__global__ __launch_bounds__(256) void qkv_kernel(
    const float* __restrict__ x, const float* __restrict__ Wq,
    const float* __restrict__ Wk, const float* __restrict__ Wv,
    ushort_t* __restrict__ split, float* __restrict__ v) {
  const size_t TSZ = (size_t)B * N * C;
  int n = blockIdx.x * 256 + threadIdx.x;
  int o0 = blockIdx.y * 4;   // 4 output channels per block -> W loads uniform
  int b = blockIdx.z;
  const float* xb = x + (size_t)b * C * N + n;
  float aq[4] = {}, ak[4] = {}, av[4] = {};
  #pragma unroll 4
  for (int c = 0; c < C; ++c) {
    float xv = xb[(size_t)c * N];
    #pragma unroll
    for (int j = 0; j < 4; ++j) {
      aq[j] = fmaf(Wq[(o0 + j) * C + c], xv, aq[j]);
      ak[j] = fmaf(Wk[(o0 + j) * C + c], xv, ak[j]);
      av[j] = fmaf(Wv[(o0 + j) * C + c], xv, av[j]);
    }
  }
  #pragma unroll
  for (int j = 0; j < 4; ++j)
    v[((size_t)b * C + o0 + j) * N + n] = av[j];
  // 3-term residual split: q = t0 + t1 + t2, residual ~2^-27
  u32 qw[3][2] = {}, kw[3][2] = {};
  #pragma unroll
  for (int j = 0; j < 4; ++j) {
    float a = aq[j];
    #pragma unroll
    for (int tt = 0; tt < 3; ++tt) {
      ushort_t h = f2bf(a);
      qw[tt][j >> 1] |= (u32)h << (16 * (j & 1));
      a -= bf2f(h);
    }
    a = ak[j];
    #pragma unroll
    for (int tt = 0; tt < 3; ++tt) {
      ushort_t h = f2bf(a);
      kw[tt][j >> 1] |= (u32)h << (16 * (j & 1));
      a -= bf2f(h);
    }
  }
  size_t tb = ((size_t)b * N + n) * C + o0;
  #pragma unroll
  for (int tt = 0; tt < 3; ++tt) {
    *(uint2*)&split[tt * TSZ + tb]       = make_uint2(qw[tt][0], qw[tt][1]);
    *(uint2*)&split[(3 + tt) * TSZ + tb] = make_uint2(kw[tt][0], kw[tt][1]);
  }
}

// ---- Ae[b,n,m] = exp(q.k/sqrt(C)) via 6-product 3-term-split MFMA ------
// rowpart[mb][b*N+n] = deterministic per-tile row partial (no atomics)
__global__ __launch_bounds__(256) void energy_kernel(
    const ushort_t* __restrict__ split,
    float* __restrict__ Ae, float* __restrict__ rowpart) {
  __shared__ union {
    ushort_t stage[48 * 512];   // 48 fragment blocks x 512 bf16 = 48 KB
    float red[128][64];
  } sh;
  __shared__ float red2[128][2];
  const size_t TSZ = (size_t)B * N * C;
  int t = threadIdx.x;
  int lane = t & 63, w = t >> 6;
  int wn = w & 1, wm = w >> 1;          // wave quadrant: n-half, m-half
  int m0 = blockIdx.x * 128, n0 = blockIdx.y * 128, b = blockIdx.z;
  f32x16 acc[2][2] = {};
  for (int c0 = 0; c0 < C; c0 += 32) {
    __syncthreads();
    #pragma unroll
    for (int j = 0; j < 12; ++j) {      // 4 waves x 12 = 48 blocks
      int bi = w * 12 + j;
      int tensor = bi >> 3;
      int rem = bi & 7, rg = rem >> 1, s = rem & 1;
      int rowbase = (tensor < 3) ? n0 : m0;
      const ushort_t* g = split + (size_t)tensor * TSZ
          + ((size_t)b * N + rowbase + rg * 32 + (lane & 31)) * C
          + c0 + s * 16 + (lane >> 5) * 8;
      async16(g, &sh.stage[bi * 512]);
    }
    __syncthreads();
    #pragma unroll
    for (int s = 0; s < 2; ++s) {
      short8 a0[2], a1[2], a2[2], b0v[2], b1v[2], b2v[2];
      #pragma unroll
      for (int i = 0; i < 2; ++i) {
        int ra = (wn * 2 + i) * 2 + s;
        int rb = (wm * 2 + i) * 2 + s;
        a0[i]  = *(const short8*)&sh.stage[(0 * 8 + ra) * 512 + lane * 8];
        a1[i]  = *(const short8*)&sh.stage[(1 * 8 + ra) * 512 + lane * 8];
        a2[i]  = *(const short8*)&sh.stage[(2 * 8 + ra) * 512 + lane * 8];
        b0v[i] = *(const short8*)&sh.stage[(3 * 8 + rb) * 512 + lane * 8];
        b1v[i] = *(const short8*)&sh.stage[(4 * 8 + rb) * 512 + lane * 8];
        b2v[i] = *(const short8*)&sh.stage[(5 * 8 + rb) * 512 + lane * 8];
      }
      #pragma unroll
      for (int mt = 0; mt < 2; ++mt)
        #pragma unroll
        for (int nt = 0; nt < 2; ++nt) {
          acc[mt][nt] = __builtin_amdgcn_mfma_f32_32x32x16_bf16(a0[mt], b0v[nt], acc[mt][nt], 0, 0, 0);
          acc[mt][nt] = __builtin_amdgcn_mfma_f32_32x32x16_bf16(a1[mt], b0v[nt], acc[mt][nt], 0, 0, 0);
          acc[mt][nt] = __builtin_amdgcn_mfma_f32_32x32x16_bf16(a0[mt], b1v[nt], acc[mt][nt], 0, 0, 0);
          acc[mt][nt] = __builtin_amdgcn_mfma_f32_32x32x16_bf16(a2[mt], b0v[nt], acc[mt][nt], 0, 0, 0);
          acc[mt][nt] = __builtin_amdgcn_mfma_f32_32x32x16_bf16(a1[mt], b1v[nt], acc[mt][nt], 0, 0, 0);
          acc[mt][nt] = __builtin_amdgcn_mfma_f32_32x32x16_bf16(a0[mt], b2v[nt], acc[mt][nt], 0, 0, 0);
        }
    }
  }
  __syncthreads();   // staging dead; reuse union as red[][]
  int lq = lane >> 5, lc = lane & 31;
  #pragma unroll
  for (int mt = 0; mt < 2; ++mt) {
    #pragma unroll
    for (int reg = 0; reg < 16; ++reg) {
      int row = (reg & 3) + 8 * (reg >> 2) + 4 * lq;   // C/D layout (m74/m101)
      int rloc = wn * 64 + mt * 32 + row;
      float e0 = expf(acc[mt][0][reg] * INV_SQRT_C);
      float e1 = expf(acc[mt][1][reg] * INV_SQRT_C);
      float* pA = Ae + ((size_t)b * N + n0 + rloc) * N + m0 + wm * 64 + lc;
      pA[0] = e0; pA[32] = e1;
      sh.red[rloc][wm * 32 + lc] = e0 + e1;   // disjoint slots, no race
    }
  }
  __syncthreads();
  {
    int row = t >> 1, h = t & 1;
    float ssum = 0.f;
    #pragma unroll
    for (int j = 0; j < 32; ++j) ssum += sh.red[row][h * 32 + j];
    red2[row][h] = ssum;
  }
  __syncthreads();
  if (t < 128)
    rowpart[(size_t)blockIdx.x * (B * N) + b * N + n0 + t] = red2[t][0] + red2[t][1];
}

// ------- invr[b,n] = 1 / (fixed-order sum of 16 row partials) ----------
__global__ __launch_bounds__(256) void rowred_kernel(
    const float* __restrict__ rowpart, float* __restrict__ invr) {
  int i = blockIdx.x * 256 + threadIdx.x;
  float s = 0.f;
  #pragma unroll
  for (int mb = 0; mb < MBLK; ++mb)
    s += rowpart[(size_t)mb * (B * N) + i];
  invr[i] = 1.0f / s;
}

// --- selpart[nch][b*N+m] = sum_{n in chunk} Ae[b,n,m] * invr[b,n] ------
__global__ __launch_bounds__(256) void colsum_kernel(
    const float* __restrict__ Ae, const float* __restrict__ invr,
    float* __restrict__ selpart) {
  int m = blockIdx.x * 256 + threadIdx.x;
  int nch = blockIdx.y, b = blockIdx.z;
  const float* Ab = Ae + (size_t)b * N * N;
  const float* ib = invr + b * N;
  float acc = 0.f;
  int n0 = nch * (N / 8);
  for (int n = n0; n < n0 + N / 8; ++n)
    acc = fmaf(Ab[(size_t)n * N + m], ib[n], acc);
  selpart[(size_t)nch * (B * N) + b * N + m] = acc;
}

// ----------- sel[b,m] = fixed-order sum of the 8 n-chunk partials -------
__global__ __launch_bounds__(256) void selred_kernel(
    const float* __restrict__ selpart, float* __restrict__ sel) {
  int i = blockIdx.x * 256 + threadIdx.x;
  float s = 0.f;
  #pragma unroll
  for (int nch = 0; nch < 8; ++nch)
    s += selpart[(size_t)nch * (B * N) + i];
  sel[i] = s;
}

// ------- exact stable-descending top-k via pairwise rank counting -------
__global__ __launch_bounds__(256) void topk_kernel(
    const float* __restrict__ sel, int* __restrict__ idx) {
  __shared__ float s[N];
  __shared__ int rsum[64][4];
  int b = blockIdx.y;
  int t = threadIdx.x;
  for (int i = t; i < N; i += 256) s[i] = sel[b * N + i];
  __syncthreads();
  int i = blockIdx.x * 64 + (t & 63);
  int jc = t >> 6;
  float val = s[i];
  int r = 0;
  for (int j = jc * 512; j < jc * 512 + 512; ++j) {
    float sj = s[j];
    r += (sj > val || (sj == val && j < i)) ? 1 : 0;
  }
  rsum[t & 63][jc] = r;
  __syncthreads();
  if (t < 64) {
    int rank = rsum[t][0] + rsum[t][1] + rsum[t][2] + rsum[t][3];
    if (rank < M) idx[b * M + rank] = blockIdx.x * 64 + t;
  }
}

// ---- out partials: part[ns][b][c][m] = sum_{n in split} w[m,n]*v[c,n] ---
__global__ __launch_bounds__(256) void out_kernel(
    const float* __restrict__ Ae, const float* __restrict__ invr,
    const float* __restrict__ v, const int* __restrict__ idx,
    float* __restrict__ part) {
  __shared__ float vt[32][133];   // [n'][c], padded stride (conflict-free)
  __shared__ float wt[32][133];   // [n'][m]
  __shared__ int ridx[128];
  __shared__ float rinv[128];
  int t = threadIdx.x;
  int m0 = blockIdx.x * 128;
  int ns = blockIdx.y;
  int b = blockIdx.z;
  if (t < 128) {
    int r = idx[b * M + m0 + t];
    ridx[t] = r;
    rinv[t] = invr[b * N + r];
  }
  __syncthreads();
  int tc = t & 15, tm = t >> 4;
  float acc[8][8] = {};
  const float* vb = v + (size_t)b * C * N;
  const float* Ab = Ae + (size_t)b * N * N;
  int nbeg = ns * (N / NSPLIT);
  for (int nb = nbeg; nb < nbeg + N / NSPLIT; nb += 32) {
    __syncthreads();
    #pragma unroll
    for (int it = 0; it < 16; ++it) {
      int ii = it * 256 + t;
      int c = ii >> 5, nn = ii & 31;
      vt[nn][c] = vb[(size_t)c * N + nb + nn];
    }
    #pragma unroll
    for (int it = 0; it < 16; ++it) {
      int ii = it * 256 + t;
      int mm = ii >> 5, nn = ii & 31;
      wt[nn][mm] = Ab[(size_t)ridx[mm] * N + nb + nn] * rinv[mm];
    }
    __syncthreads();
    #pragma unroll
    for (int nn = 0; nn < 32; ++nn) {
      float4 a0 = *(const float4*)&vt[nn][tc * 8];
      float4 a1 = *(const float4*)&vt[nn][tc * 8 + 4];
      float4 b0 = *(const float4*)&wt[nn][tm * 8];
      float4 b1 = *(const float4*)&wt[nn][tm * 8 + 4];
      float av[8] = {a0.x, a0.y, a0.z, a0.w, a1.x, a1.y, a1.z, a1.w};
      float wv[8] = {b0.x, b0.y, b0.z, b0.w, b1.x, b1.y, b1.z, b1.w};
      #pragma unroll
      for (int ci = 0; ci < 8; ++ci)
        #pragma unroll
        for (int mj = 0; mj < 8; ++mj)
          acc[ci][mj] = fmaf(av[ci], wv[mj], acc[ci][mj]);
    }
  }
  float* pb = part + ((size_t)ns * B + b) * C * M;
  #pragma unroll
  for (int ci = 0; ci < 8; ++ci) {
    size_t rowoff = (size_t)(tc * 8 + ci) * M + m0 + tm * 8;
    *(float4*)&pb[rowoff] = make_float4(acc[ci][0], acc[ci][1], acc[ci][2], acc[ci][3]);
    *(float4*)&pb[rowoff + 4] = make_float4(acc[ci][4], acc[ci][5], acc[ci][6], acc[ci][7]);
  }
}

// ----------------- deterministic reduce of the n-splits -----------------
__global__ __launch_bounds__(256) void reduce_kernel(
    const float* __restrict__ part, float* __restrict__ out) {
  int i = blockIdx.x * 256 + threadIdx.x;
  float a = 0.f;
  #pragma unroll
  for (int ns = 0; ns < NSPLIT; ++ns)
    a += part[(size_t)ns * (B * C * M) + i];
  out[i] = a;
}

extern "C" void kernel_launch(void* const* d_in, const int* in_sizes, int n_in,
                              void* d_out, int out_size, void* d_ws, size_t ws_size,
                              hipStream_t stream) {
  const float* x  = (const float*)d_in[0];
  const float* Wq = (const float*)d_in[1];
  const float* Wk = (const float*)d_in[2];
  const float* Wv = (const float*)d_in[3];
  float* out = (float*)d_out;

  const size_t TSZ = (size_t)B * N * C;
  ushort_t* split = (ushort_t*)d_ws;                // 6 * TSZ bf16 = 25.2 MB
  float* v       = (float*)(split + 6 * TSZ);       // 8.4 MB
  float* Ae      = v + (size_t)B * C * N;           // 134.2 MB
  float* rowpart = Ae + (size_t)B * N * N;          // 16 * B*N
  float* invr    = rowpart + (size_t)MBLK * B * N;  // B*N
  float* selpart = invr + (size_t)B * N;            // 8 * B*N
  float* sel     = selpart + (size_t)8 * B * N;     // B*N
  int*   idx     = (int*)(sel + (size_t)B * N);     // B*M
  // part overlays split (dead after energy): NSPLIT*B*C*M fp32 = 16.8MB <= 25.2MB
  float* part    = (float*)split;

  qkv_kernel<<<dim3(N / 256, C / 4, B), 256, 0, stream>>>(x, Wq, Wk, Wv, split, v);
  energy_kernel<<<dim3(N / 128, N / 128, B), 256, 0, stream>>>(split, Ae, rowpart);
  rowred_kernel<<<dim3(B * N / 256), 256, 0, stream>>>(rowpart, invr);
  colsum_kernel<<<dim3(N / 256, 8, B), 256, 0, stream>>>(Ae, invr, selpart);
  selred_kernel<<<dim3(B * N / 256), 256, 0, stream>>>(selpart, sel);
  topk_kernel<<<dim3(N / 64, B), 256, 0, stream>>>(sel, idx);
  out_kernel<<<dim3(M / 128, NSPLIT, B), 256, 0, stream>>>(Ae, invr, v, idx, part);
  reduce_kernel<<<dim3(B * C * M / 256), 256, 0, stream>>>(part, out);
}

// Round 5
// 276.913 us; speedup vs baseline: 1.2829x; 1.1838x over previous
//
#include <hip/hip_runtime.h>
#include <math.h>

namespace {
constexpr int B = 8, C = 128, N = 2048, M = 512;
constexpr int NSPLIT = 8;       // part (NSPLIT*B*C*M fp32 = 16.8MB) must fit split region (25.2MB)
constexpr int MBLK = N / 128;   // 16 m-tiles per row in energy
constexpr float INV_SQRT_C = 0.08838834764831845f;  // 1/sqrt(128)
}

typedef __attribute__((ext_vector_type(8))) short short8;
typedef __attribute__((ext_vector_type(16))) float f32x16;
typedef unsigned short ushort_t;
typedef unsigned int u32;

__device__ inline ushort_t f2bf(float f) {   // round-to-nearest-even bf16
  union { float f; u32 u; } a; a.f = f;
  u32 r = a.u + 0x7fffu + ((a.u >> 16) & 1u);
  return (ushort_t)(r >> 16);
}
__device__ inline float bf2f(ushort_t h) {
  union { u32 u; float f; } a; a.u = ((u32)h) << 16; return a.f;
}

// -- q,k: 3-term bf16 split, k-chunk-major [term][b][kc][n][8]; v: [b][c][n] --
// grid (16 kc, 8 nblk, B): 16 consecutive blocks share one x-chunk -> L2 reuse
__global__ __launch_bounds__(256) void qkv_kernel(
    const float* __restrict__ x, const float* __restrict__ Wq,
    const float* __restrict__ Wk, const float* __restrict__ Wv,
    ushort_t* __restrict__ split, float* __restrict__ v) {
  const size_t TERM = (size_t)B * N * C;
  int kc = blockIdx.x;             // output-channel chunk (8 channels)
  int o0 = kc * 8;
  int n = blockIdx.y * 256 + threadIdx.x;
  int b = blockIdx.z;
  const float* xb = x + (size_t)b * C * N + n;
  float aq[8] = {}, ak[8] = {}, av[8] = {};
  #pragma unroll 4
  for (int c = 0; c < C; ++c) {
    float xv = xb[(size_t)c * N];
    #pragma unroll
    for (int j = 0; j < 8; ++j) {   // W loads wave-uniform -> s_loads
      aq[j] = fmaf(Wq[(o0 + j) * C + c], xv, aq[j]);
      ak[j] = fmaf(Wk[(o0 + j) * C + c], xv, ak[j]);
      av[j] = fmaf(Wv[(o0 + j) * C + c], xv, av[j]);
    }
  }
  #pragma unroll
  for (int j = 0; j < 8; ++j)
    v[((size_t)b * C + o0 + j) * N + n] = av[j];
  // 3-term residual split, one full 16B fragment unit per (term, n)
  size_t rowoff = ((size_t)b * 16 + kc) * (size_t)N * 8 + (size_t)n * 8;
  #pragma unroll
  for (int tt = 0; tt < 3; ++tt) {
    short8 qv, kv;
    #pragma unroll
    for (int j = 0; j < 8; ++j) {
      ushort_t h = f2bf(aq[j]); qv[j] = (short)h; aq[j] -= bf2f(h);
      h = f2bf(ak[j]);          kv[j] = (short)h; ak[j] -= bf2f(h);
    }
    *(short8*)&split[tt * TERM + rowoff]       = qv;
    *(short8*)&split[(3 + tt) * TERM + rowoff] = kv;
  }
}

// ---- Ae[b,n,m] = exp(q.k/sqrt(C)) via 6-product 3-term-split MFMA ------
// Direct global fragment loads (no LDS staging, no K-loop barriers).
// rowpart[mb][b*N+n] = deterministic per-tile row partial (no atomics)
__global__ __launch_bounds__(256) void energy_kernel(
    const ushort_t* __restrict__ split,
    float* __restrict__ Ae, float* __restrict__ rowpart) {
  __shared__ float red[128][64];   // 32 KB
  __shared__ float red2[128][2];
  const size_t TERM = (size_t)B * N * C;
  const size_t ROW8 = (size_t)N * 8;       // elements per kc-row
  int t = threadIdx.x;
  int lane = t & 63, w = t >> 6;
  int wn = w & 1, wm = w >> 1;             // wave quadrant
  // 4x4 supertile swizzle for L2 locality
  int lin = blockIdx.y * 16 + blockIdx.x;
  int st = lin >> 4, wi = lin & 15;
  int mb = (st & 3) * 4 + (wi & 3);
  int nb = (st >> 2) * 4 + (wi >> 2);
  int m0 = mb * 128, n0 = nb * 128, b = blockIdx.z;
  int lr = lane & 31, lq = lane >> 5;
  size_t kbase = ((size_t)b * 16 + lq) * ROW8;
  const ushort_t* Abase = split + kbase + (size_t)(n0 + wn * 64 + lr) * 8;
  const ushort_t* Bbase = split + 3 * TERM + kbase + (size_t)(m0 + wm * 64 + lr) * 8;
  f32x16 acc[2][2] = {};
  #pragma unroll
  for (int s = 0; s < 8; ++s) {            // K = 8 steps x 16
    size_t so = (size_t)s * 2 * ROW8;
    short8 aT[3][2], bT[3][2];
    #pragma unroll
    for (int tt = 0; tt < 3; ++tt)
      #pragma unroll
      for (int i = 0; i < 2; ++i) {        // i = 32-point sub-tile
        aT[tt][i] = *(const short8*)(Abase + tt * TERM + so + i * 256);
        bT[tt][i] = *(const short8*)(Bbase + tt * TERM + so + i * 256);
      }
    #pragma unroll
    for (int mt = 0; mt < 2; ++mt)
      #pragma unroll
      for (int nt = 0; nt < 2; ++nt) {
        acc[mt][nt] = __builtin_amdgcn_mfma_f32_32x32x16_bf16(aT[0][mt], bT[0][nt], acc[mt][nt], 0, 0, 0);
        acc[mt][nt] = __builtin_amdgcn_mfma_f32_32x32x16_bf16(aT[1][mt], bT[0][nt], acc[mt][nt], 0, 0, 0);
        acc[mt][nt] = __builtin_amdgcn_mfma_f32_32x32x16_bf16(aT[0][mt], bT[1][nt], acc[mt][nt], 0, 0, 0);
        acc[mt][nt] = __builtin_amdgcn_mfma_f32_32x32x16_bf16(aT[2][mt], bT[0][nt], acc[mt][nt], 0, 0, 0);
        acc[mt][nt] = __builtin_amdgcn_mfma_f32_32x32x16_bf16(aT[1][mt], bT[1][nt], acc[mt][nt], 0, 0, 0);
        acc[mt][nt] = __builtin_amdgcn_mfma_f32_32x32x16_bf16(aT[0][mt], bT[2][nt], acc[mt][nt], 0, 0, 0);
      }
  }
  int lc = lr;
  #pragma unroll
  for (int mt = 0; mt < 2; ++mt) {
    #pragma unroll
    for (int reg = 0; reg < 16; ++reg) {
      int row = (reg & 3) + 8 * (reg >> 2) + 4 * lq;   // C/D layout (m74/m101)
      int rloc = wn * 64 + mt * 32 + row;
      float e0 = expf(acc[mt][0][reg] * INV_SQRT_C);
      float e1 = expf(acc[mt][1][reg] * INV_SQRT_C);
      float* pA = Ae + ((size_t)b * N + n0 + rloc) * N + m0 + wm * 64 + lc;
      pA[0] = e0; pA[32] = e1;
      red[rloc][wm * 32 + lc] = e0 + e1;   // disjoint slots, no race
    }
  }
  __syncthreads();
  {
    int row = t >> 1, h = t & 1;
    float ssum = 0.f;
    #pragma unroll
    for (int j0 = 0; j0 < 32; ++j0) {
      int j = (j0 + (t & 31)) & 31;        // bank rotation: 2-way max (free)
      ssum += red[row][h * 32 + j];
    }
    red2[row][h] = ssum;
  }
  __syncthreads();
  if (t < 128)
    rowpart[(size_t)mb * (B * N) + b * N + n0 + t] = red2[t][0] + red2[t][1];
}

// ------- invr[b,n] = 1 / (fixed-order sum of 16 row partials) ----------
__global__ __launch_bounds__(256) void rowred_kernel(
    const float* __restrict__ rowpart, float* __restrict__ invr) {
  int i = blockIdx.x * 256 + threadIdx.x;
  float s = 0.f;
  #pragma unroll
  for (int mb = 0; mb < MBLK; ++mb)
    s += rowpart[(size_t)mb * (B * N) + i];
  invr[i] = 1.0f / s;
}

// --- selpart[nch][b*N+m] = sum_{n in chunk} Ae[b,n,m] * invr[b,n] ------
__global__ __launch_bounds__(256) void colsum_kernel(
    const float* __restrict__ Ae, const float* __restrict__ invr,
    float* __restrict__ selpart) {
  int m = blockIdx.x * 256 + threadIdx.x;
  int nch = blockIdx.y, b = blockIdx.z;
  const float* Ab = Ae + (size_t)b * N * N;
  const float* ib = invr + b * N;
  float acc = 0.f;
  int n0 = nch * (N / 8);
  for (int n = n0; n < n0 + N / 8; ++n)
    acc = fmaf(Ab[(size_t)n * N + m], ib[n], acc);
  selpart[(size_t)nch * (B * N) + b * N + m] = acc;
}

// ----------- sel[b,m] = fixed-order sum of the 8 n-chunk partials -------
__global__ __launch_bounds__(256) void selred_kernel(
    const float* __restrict__ selpart, float* __restrict__ sel) {
  int i = blockIdx.x * 256 + threadIdx.x;
  float s = 0.f;
  #pragma unroll
  for (int nch = 0; nch < 8; ++nch)
    s += selpart[(size_t)nch * (B * N) + i];
  sel[i] = s;
}

// ------- exact stable-descending top-k via pairwise rank counting -------
__global__ __launch_bounds__(256) void topk_kernel(
    const float* __restrict__ sel, int* __restrict__ idx) {
  __shared__ float s[N];
  __shared__ int rsum[64][4];
  int b = blockIdx.y;
  int t = threadIdx.x;
  for (int i = t; i < N; i += 256) s[i] = sel[b * N + i];
  __syncthreads();
  int i = blockIdx.x * 64 + (t & 63);
  int jc = t >> 6;
  float val = s[i];
  int r = 0;
  for (int j = jc * 512; j < jc * 512 + 512; ++j) {
    float sj = s[j];
    r += (sj > val || (sj == val && j < i)) ? 1 : 0;
  }
  rsum[t & 63][jc] = r;
  __syncthreads();
  if (t < 64) {
    int rank = rsum[t][0] + rsum[t][1] + rsum[t][2] + rsum[t][3];
    if (rank < M) idx[b * M + rank] = blockIdx.x * 64 + t;
  }
}

// ---- out partials: part[ns][b][c][m] = sum_{n in split} w[m,n]*v[c,n] ---
__global__ __launch_bounds__(256) void out_kernel(
    const float* __restrict__ Ae, const float* __restrict__ invr,
    const float* __restrict__ v, const int* __restrict__ idx,
    float* __restrict__ part) {
  __shared__ float vt[32][133];   // [n'][c], padded stride (conflict-free)
  __shared__ float wt[32][133];   // [n'][m]
  __shared__ int ridx[128];
  __shared__ float rinv[128];
  int t = threadIdx.x;
  int m0 = blockIdx.x * 128;
  int ns = blockIdx.y;
  int b = blockIdx.z;
  if (t < 128) {
    int r = idx[b * M + m0 + t];
    ridx[t] = r;
    rinv[t] = invr[b * N + r];
  }
  __syncthreads();
  int tc = t & 15, tm = t >> 4;
  float acc[8][8] = {};
  const float* vb = v + (size_t)b * C * N;
  const float* Ab = Ae + (size_t)b * N * N;
  int nbeg = ns * (N / NSPLIT);
  for (int nb = nbeg; nb < nbeg + N / NSPLIT; nb += 32) {
    __syncthreads();
    #pragma unroll
    for (int it = 0; it < 16; ++it) {
      int ii = it * 256 + t;
      int c = ii >> 5, nn = ii & 31;
      vt[nn][c] = vb[(size_t)c * N + nb + nn];
    }
    #pragma unroll
    for (int it = 0; it < 16; ++it) {
      int ii = it * 256 + t;
      int mm = ii >> 5, nn = ii & 31;
      wt[nn][mm] = Ab[(size_t)ridx[mm] * N + nb + nn] * rinv[mm];
    }
    __syncthreads();
    #pragma unroll
    for (int nn = 0; nn < 32; ++nn) {
      float4 a0 = *(const float4*)&vt[nn][tc * 8];
      float4 a1 = *(const float4*)&vt[nn][tc * 8 + 4];
      float4 b0 = *(const float4*)&wt[nn][tm * 8];
      float4 b1 = *(const float4*)&wt[nn][tm * 8 + 4];
      float av[8] = {a0.x, a0.y, a0.z, a0.w, a1.x, a1.y, a1.z, a1.w};
      float wv[8] = {b0.x, b0.y, b0.z, b0.w, b1.x, b1.y, b1.z, b1.w};
      #pragma unroll
      for (int ci = 0; ci < 8; ++ci)
        #pragma unroll
        for (int mj = 0; mj < 8; ++mj)
          acc[ci][mj] = fmaf(av[ci], wv[mj], acc[ci][mj]);
    }
  }
  float* pb = part + ((size_t)ns * B + b) * C * M;
  #pragma unroll
  for (int ci = 0; ci < 8; ++ci) {
    size_t rowoff = (size_t)(tc * 8 + ci) * M + m0 + tm * 8;
    *(float4*)&pb[rowoff] = make_float4(acc[ci][0], acc[ci][1], acc[ci][2], acc[ci][3]);
    *(float4*)&pb[rowoff + 4] = make_float4(acc[ci][4], acc[ci][5], acc[ci][6], acc[ci][7]);
  }
}

// ----------------- deterministic reduce of the n-splits -----------------
__global__ __launch_bounds__(256) void reduce_kernel(
    const float* __restrict__ part, float* __restrict__ out) {
  int i = blockIdx.x * 256 + threadIdx.x;
  float a = 0.f;
  #pragma unroll
  for (int ns = 0; ns < NSPLIT; ++ns)
    a += part[(size_t)ns * (B * C * M) + i];
  out[i] = a;
}

extern "C" void kernel_launch(void* const* d_in, const int* in_sizes, int n_in,
                              void* d_out, int out_size, void* d_ws, size_t ws_size,
                              hipStream_t stream) {
  const float* x  = (const float*)d_in[0];
  const float* Wq = (const float*)d_in[1];
  const float* Wk = (const float*)d_in[2];
  const float* Wv = (const float*)d_in[3];
  float* out = (float*)d_out;

  const size_t TSZ = (size_t)B * N * C;
  ushort_t* split = (ushort_t*)d_ws;                // 6 * TSZ bf16 = 25.2 MB
  float* v       = (float*)(split + 6 * TSZ);       // 8.4 MB
  float* Ae      = v + (size_t)B * C * N;           // 134.2 MB
  float* rowpart = Ae + (size_t)B * N * N;          // 16 * B*N
  float* invr    = rowpart + (size_t)MBLK * B * N;  // B*N
  float* selpart = invr + (size_t)B * N;            // 8 * B*N
  float* sel     = selpart + (size_t)8 * B * N;     // B*N
  int*   idx     = (int*)(sel + (size_t)B * N);     // B*M
  // part overlays split (dead after energy): NSPLIT*B*C*M fp32 = 16.8MB <= 25.2MB
  float* part    = (float*)split;

  qkv_kernel<<<dim3(16, N / 256, B), 256, 0, stream>>>(x, Wq, Wk, Wv, split, v);
  energy_kernel<<<dim3(N / 128, N / 128, B), 256, 0, stream>>>(split, Ae, rowpart);
  rowred_kernel<<<dim3(B * N / 256), 256, 0, stream>>>(rowpart, invr);
  colsum_kernel<<<dim3(N / 256, 8, B), 256, 0, stream>>>(Ae, invr, selpart);
  selred_kernel<<<dim3(B * N / 256), 256, 0, stream>>>(selpart, sel);
  topk_kernel<<<dim3(N / 64, B), 256, 0, stream>>>(sel, idx);
  out_kernel<<<dim3(M / 128, NSPLIT, B), 256, 0, stream>>>(Ae, invr, v, idx, part);
  reduce_kernel<<<dim3(B * C * M / 256), 256, 0, stream>>>(part, out);
}